// Round 18
// baseline (558.771 us; speedup 1.0000x reference)
//
#include <hip/hip_runtime.h>
#include <math.h>

// CollapseEngine R18: R15 base (16x16x32, validated phi layout, force+stats
// folds, counted-vmcnt pipeline) with TWO batch tiles per wave (32 rows):
// each A-frag ds_read feeds 2 MFMAs -> LDS reads per row halve; 256 rows/block
// -> 2 block-rounds. No new layout assumptions (R16/R17's 32x32 failed twice
// on unverifiable operand geometry). ac lives in AGPRs (unified file,
// 2 waves/SIMD -> ample budget); launch_bounds(512,1).
// phi(ks,G,i) = 32*ks + 16*(i>>2) + 4*G + (i&3),  G = lane>>4.

#define DIMX 256
#define NL 6
#define CPAD 68

typedef float f32x4 __attribute__((ext_vector_type(4)));
typedef short short8 __attribute__((ext_vector_type(8)));
typedef unsigned int u32x4 __attribute__((ext_vector_type(4)));

#define CHB(c) ((c) * 1024)
#define EXTB 16384      // ext A-frags (G2 force fold): 1024 granules
#define STATB 17408     // stats A-frags: 512 granules

// RNE-pack f32 pair -> u32 of 2 bf16 (lo = X0, hi = X1)
#define PACKB(X0, X1, DST)                                                       \
    asm("v_cvt_pk_bf16_f32 %0, %1, %2" : "=v"(DST) : "v"(X0), "v"(X1));

// ---------------- W frag + ext/stat frag precompute (= R15, verbatim) ----------
__global__ void wsplit(const float* __restrict__ W1, const float* __restrict__ W2,
                       const float* __restrict__ anchors, const float* __restrict__ b2f,
                       u32x4* __restrict__ ws) {
    int gi = blockIdx.x * 256 + threadIdx.x;        // 0..17919
    if (gi < 16384) {
        int ln   = gi & 63;
        int t8   = (gi >> 6) & 7;
        int ks2  = (gi >> 9) & 1;
        int kk   = (gi >> 10) & 3;
        int pass = (gi >> 12) & 1;
        int g    = (gi >> 13) & 1;
        int ks   = kk * 2 + ks2;
        int m    = (pass * 8 + t8) * 16 + (ln & 15);
        int G    = ln >> 4;
        const float* Wg = g ? W2 : W1;
        unsigned o[4];
#pragma unroll
        for (int p = 0; p < 4; ++p) {
            int f = 32 * ks + ((p >> 1) << 4) + 4 * G + ((p & 1) << 1);
            float x0 = Wg[m * DIMX + f];
            float x1 = Wg[m * DIMX + f + 1];
            unsigned hp;
            PACKB(x0, x1, hp);
            o[p] = hp;
        }
        u32x4 out = {o[0], o[1], o[2], o[3]};
        ws[gi] = out;
    } else if (gi < STATB) {
        int r    = gi - EXTB;
        int pass = r >> 9;
        int t8   = (r >> 6) & 7;
        int ln   = r & 63;
        int m    = ln & 15;
        int G    = ln >> 4;
        int fout = (pass * 8 + t8) * 16 + m;
        float inv[3];
#pragma unroll
        for (int k = 0; k < 3; ++k) {
            float ss = 0.0f;
            for (int f = 0; f < DIMX; ++f) { float a = anchors[k*DIMX+f]; ss += a*a; }
            inv[k] = 1.0f / fmaxf(sqrtf(ss), 1e-12f);
        }
        float v[8];
#pragma unroll
        for (int i = 0; i < 8; ++i) {
            int k = G * 8 + i;
            v[i] = (k == 0) ? -anchors[fout] * inv[0]
                 : (k == 1) ? -anchors[DIMX + fout] * inv[1]
                 : (k == 2) ? -anchors[2 * DIMX + fout] * inv[2]
                 : (k == 3) ? b2f[fout] : 0.0f;
        }
        unsigned o[4];
#pragma unroll
        for (int p = 0; p < 4; ++p) { unsigned hp; PACKB(v[2*p], v[2*p+1], hp); o[p] = hp; }
        u32x4 out = {o[0], o[1], o[2], o[3]};
        ws[gi] = out;
    } else if (gi < STATB + 512) {
        int r  = gi - STATB;
        int ks = r >> 6;
        int ln = r & 63;
        int m  = ln & 15;
        int G  = ln >> 4;
        float inv = 0.0f;
        if (m < 3) {
            float ss = 0.0f;
            for (int f = 0; f < DIMX; ++f) { float a = anchors[m*DIMX+f]; ss += a*a; }
            inv = 1.0f / fmaxf(sqrtf(ss), 1e-12f);
        }
        float v[8];
#pragma unroll
        for (int i = 0; i < 8; ++i) {
            int f = 32 * ks + 16 * (i >> 2) + 4 * G + (i & 3);
            v[i] = (m < 3) ? anchors[m * DIMX + f] * inv : 0.0f;
        }
        unsigned o[4];
#pragma unroll
        for (int p = 0; p < 4; ++p) { unsigned hp; PACKB(v[2*p], v[2*p+1], hp); o[p] = hp; }
        u32x4 out = {o[0], o[1], o[2], o[3]};
        ws[gi] = out;
    }
}

// ---------------- main fused kernel ----------------

#define STAGE(gIdxBase, ldsSlotBase)                                             \
    {                                                                            \
        _Pragma("unroll")                                                        \
        for (int i_ = 0; i_ < 2; ++i_) {                                         \
            const int off_ = ((w * 2 + i_) << 6);                                \
            __builtin_amdgcn_global_load_lds(                                    \
                (const __attribute__((address_space(1))) void*)(ws + (gIdxBase) + off_ + lane), \
                (__attribute__((address_space(3))) void*)(&wf[(ldsSlotBase) + off_]),           \
                16, 0, 0);                                                       \
        }                                                                        \
    }

#define PIPE_SYNC()                                                              \
    {                                                                            \
        asm volatile("s_waitcnt vmcnt(4)" ::: "memory");                         \
        __builtin_amdgcn_sched_barrier(0);                                       \
        __builtin_amdgcn_s_barrier();                                            \
        __builtin_amdgcn_sched_barrier(0);                                       \
    }

__global__ __launch_bounds__(512, 1)
void collapse_mfma16(const float* __restrict__ h0,
                     const float* __restrict__ b1f,
                     const u32x4* __restrict__ ws,
                     float* __restrict__ out_h,
                     float* __restrict__ out_align,
                     float* __restrict__ out_div,
                     float* __restrict__ out_tens,
                     int B)
{
    __shared__ __align__(16) u32x4 wf[4096];         // 4 x 16KB W-frag buffers
    __shared__ __align__(16) u32x4 wext[1024];       // 16KB ext A-frags
    __shared__ __align__(16) u32x4 wstat[512];       // 8KB stats A-frags
    __shared__ __align__(16) float b1_reg[272];

    const int tid  = threadIdx.x;
    const int w    = tid >> 6;
    const int lane = tid & 63;
    const int G    = lane >> 4;
    const int c    = lane & 15;
    const int bg   = blockIdx.x * 256 + w * 32 + c;   // tile0 row; tile1 = bg+16

    // static frags first (drained by init __syncthreads)
    {
#pragma unroll
        for (int i_ = 0; i_ < 2; ++i_) {
            const int off_ = ((w * 2 + i_) << 6);
            __builtin_amdgcn_global_load_lds(
                (const __attribute__((address_space(1))) void*)(ws + EXTB + off_ + lane),
                (__attribute__((address_space(3))) void*)(&wext[off_]),
                16, 0, 0);
        }
        __builtin_amdgcn_global_load_lds(
            (const __attribute__((address_space(1))) void*)(ws + STATB + w*64 + lane),
            (__attribute__((address_space(3))) void*)(&wstat[w*64]),
            16, 0, 0);
    }

    // b1 in phi-layout, padded
    {
        int idx = tid & 255;
        int Gc = idx >> 6, s = idx & 63;
        int f = 16 * (s >> 2) + 4 * Gc + (s & 3);
        if (tid < 256) b1_reg[Gc * CPAD + s] = b1f[f];
    }
    __syncthreads();

    // load h0: hr[bt][mt*4+r] = h0[bg+16bt][16mt+4G+r]
    float hr[2][64];
#pragma unroll
    for (int bt = 0; bt < 2; ++bt) {
#pragma unroll
        for (int mt = 0; mt < 16; ++mt) {
            const float4 v = *(const float4*)
                &h0[(size_t)(bg + bt*16) * DIMX + 16 * mt + 4 * G];
            hr[bt][mt*4+0] = v.x; hr[bt][mt*4+1] = v.y;
            hr[bt][mt*4+2] = v.z; hr[bt][mt*4+3] = v.w;
        }
    }

    STAGE(CHB(0), 0);
    STAGE(CHB(1), 1024);
    STAGE(CHB(2), 2048);

#pragma unroll 1
    for (int layer = 0; layer < NL; ++layer) {
        // ---------- p0 = |h|^2 per tile ----------
        float p0[2];
#pragma unroll
        for (int bt = 0; bt < 2; ++bt) {
            float s_ = 0.0f;
#pragma unroll
            for (int s = 0; s < 64; ++s) s_ += hr[bt][s] * hr[bt][s];
            s_ += __shfl_xor(s_, 16);
            s_ += __shfl_xor(s_, 32);
            p0[bt] = s_;
        }

        // ---------- G1 (+ stats tile in pass 0), dual B-tiles ----------
        unsigned tph[2][32];
        f32x4 acs[2];
        acs[0] = (f32x4)(0.0f); acs[1] = (f32x4)(0.0f);
#pragma unroll
        for (int pass = 0; pass < 2; ++pass) {
            f32x4 ac[2][8];
#pragma unroll
            for (int bt = 0; bt < 2; ++bt)
#pragma unroll
                for (int j = 0; j < 8; ++j) ac[bt][j] = (f32x4)(0.0f);
#pragma unroll
            for (int kk = 0; kk < 4; ++kk) {
                const int s = pass * 4 + kk;
                PIPE_SYNC();
                STAGE(CHB((s + 3) & 15), ((s + 3) & 3) * 1024);
                const int cb = (s & 3) * 1024;
#pragma unroll
                for (int ks2 = 0; ks2 < 2; ++ks2) {
                    const int ks = kk * 2 + ks2;
                    short8 Bh[2];
#pragma unroll
                    for (int bt = 0; bt < 2; ++bt) {
                        unsigned b0_, b1_, b2_, b3_;
                        PACKB(hr[bt][8*ks+0], hr[bt][8*ks+1], b0_);
                        PACKB(hr[bt][8*ks+2], hr[bt][8*ks+3], b1_);
                        PACKB(hr[bt][8*ks+4], hr[bt][8*ks+5], b2_);
                        PACKB(hr[bt][8*ks+6], hr[bt][8*ks+7], b3_);
                        u32x4 bv = {b0_, b1_, b2_, b3_};
                        Bh[bt] = __builtin_bit_cast(short8, bv);
                    }
#pragma unroll
                    for (int j = 0; j < 8; ++j) {
                        const short8 Ah = __builtin_bit_cast(short8,
                            wf[cb + ks2*512 + j*64 + lane]);
                        ac[0][j] = __builtin_amdgcn_mfma_f32_16x16x32_bf16(Ah, Bh[0], ac[0][j], 0, 0, 0);
                        ac[1][j] = __builtin_amdgcn_mfma_f32_16x16x32_bf16(Ah, Bh[1], ac[1][j], 0, 0, 0);
                    }
                    if (pass == 0) {
                        const short8 As = __builtin_bit_cast(short8, wstat[ks*64 + lane]);
                        acs[0] = __builtin_amdgcn_mfma_f32_16x16x32_bf16(As, Bh[0], acs[0], 0, 0, 0);
                        acs[1] = __builtin_amdgcn_mfma_f32_16x16x32_bf16(As, Bh[1], acs[1], 0, 0, 0);
                    }
                }
            }
            // tanh + b1, pack into tph per tile
#pragma unroll
            for (int j = 0; j < 8; ++j) {
                const int mt = pass * 8 + j;
                const float4 bq = *(const float4*)&b1_reg[G * CPAD + mt * 4];
                const int ti = 4 * (mt >> 1) + 2 * (mt & 1);
#pragma unroll
                for (int bt = 0; bt < 2; ++bt) {
                    float tv[4];
#pragma unroll
                    for (int r = 0; r < 4; ++r) {
                        float x = ac[bt][j][r] + ((r==0)?bq.x:(r==1)?bq.y:(r==2)?bq.z:bq.w);
                        float e = __expf(2.0f * x);
                        tv[r] = 1.0f - 2.0f * __builtin_amdgcn_rcpf(e + 1.0f);
                    }
                    PACKB(tv[0], tv[1], tph[bt][ti]);
                    PACKB(tv[2], tv[3], tph[bt][ti + 1]);
                }
            }
        }

        // ---------- stats finish per tile ----------
        float csum[2];
        unsigned be0[2] = {0u, 0u}, be1[2] = {0u, 0u};
#pragma unroll
        for (int bt = 0; bt < 2; ++bt) {
            const float d0 = acs[bt][0], d1 = acs[bt][1], d2 = acs[bt][2];
            const float inv_rn = 1.0f / fmaxf(sqrtf(p0[bt]), 1e-12f);
            const float al0 = d0*inv_rn, al1 = d1*inv_rn, al2 = d2*inv_rn;
            const float dv0 = 1.0f-al0, dv1 = 1.0f-al1, dv2 = 1.0f-al2;
            const float c0 = -0.10f*dv0 / fmaxf(sqrtf(fmaxf(p0[bt]-2.0f*d0+1.0f, 0.0f)), 1e-12f);
            const float c1 = -0.10f*dv1 / fmaxf(sqrtf(fmaxf(p0[bt]-2.0f*d1+1.0f, 0.0f)), 1e-12f);
            const float c2 = -0.05f*dv2 / fmaxf(sqrtf(fmaxf(p0[bt]-2.0f*d2+1.0f, 0.0f)), 1e-12f);
            if (G == 0) {
                const long long tb = ((long long)layer * B + (bg + bt*16)) * 3;
                out_align[tb+0] = al0; out_align[tb+1] = al1; out_align[tb+2] = al2;
                out_div[tb+0] = dv0;   out_div[tb+1] = dv1;   out_div[tb+2] = dv2;
                out_tens[tb+0] = dv0*dv0; out_tens[tb+1] = dv1*dv1; out_tens[tb+2] = dv2*dv2;
                PACKB(c0, c1, be0[bt]);
                PACKB(c2, 1.0f, be1[bt]);
            }
            float cs = 1.0f + c0 + c1 + c2;
            csum[bt] = __shfl(cs, c);
        }

        // ---------- G2: h' = csum*h + ext(rank4) + W2 t ----------
        short8 Bext[2];
#pragma unroll
        for (int bt = 0; bt < 2; ++bt) {
            u32x4 bev = {be0[bt], be1[bt], 0u, 0u};
            Bext[bt] = __builtin_bit_cast(short8, bev);
        }
#pragma unroll
        for (int pass = 0; pass < 2; ++pass) {
            f32x4 ac[2][8];
#pragma unroll
            for (int j = 0; j < 8; ++j) {
                const int mt = pass * 8 + j;
#pragma unroll
                for (int bt = 0; bt < 2; ++bt) {
                    ac[bt][j][0] = hr[bt][mt*4+0]*csum[bt];
                    ac[bt][j][1] = hr[bt][mt*4+1]*csum[bt];
                    ac[bt][j][2] = hr[bt][mt*4+2]*csum[bt];
                    ac[bt][j][3] = hr[bt][mt*4+3]*csum[bt];
                }
            }
#pragma unroll
            for (int j = 0; j < 8; ++j) {
                const short8 Ax = __builtin_bit_cast(short8, wext[pass*512 + j*64 + lane]);
                ac[0][j] = __builtin_amdgcn_mfma_f32_16x16x32_bf16(Ax, Bext[0], ac[0][j], 0, 0, 0);
                ac[1][j] = __builtin_amdgcn_mfma_f32_16x16x32_bf16(Ax, Bext[1], ac[1][j], 0, 0, 0);
            }
#pragma unroll
            for (int kk = 0; kk < 4; ++kk) {
                const int s = 8 + pass * 4 + kk;
                PIPE_SYNC();
                STAGE(CHB((s + 3) & 15), ((s + 3) & 3) * 1024);
                const int cb = (s & 3) * 1024;
#pragma unroll
                for (int ks2 = 0; ks2 < 2; ++ks2) {
                    const int ks = kk * 2 + ks2;
                    short8 Bh[2];
#pragma unroll
                    for (int bt = 0; bt < 2; ++bt) {
                        u32x4 bv = {tph[bt][4*ks+0], tph[bt][4*ks+1],
                                    tph[bt][4*ks+2], tph[bt][4*ks+3]};
                        Bh[bt] = __builtin_bit_cast(short8, bv);
                    }
#pragma unroll
                    for (int j = 0; j < 8; ++j) {
                        const short8 Ah = __builtin_bit_cast(short8,
                            wf[cb + ks2*512 + j*64 + lane]);
                        ac[0][j] = __builtin_amdgcn_mfma_f32_16x16x32_bf16(Ah, Bh[0], ac[0][j], 0, 0, 0);
                        ac[1][j] = __builtin_amdgcn_mfma_f32_16x16x32_bf16(Ah, Bh[1], ac[1][j], 0, 0, 0);
                    }
                }
            }
#pragma unroll
            for (int j = 0; j < 8; ++j) {
                const int mt = pass * 8 + j;
#pragma unroll
                for (int bt = 0; bt < 2; ++bt) {
                    hr[bt][mt*4+0] = ac[bt][j][0]; hr[bt][mt*4+1] = ac[bt][j][1];
                    hr[bt][mt*4+2] = ac[bt][j][2]; hr[bt][mt*4+3] = ac[bt][j][3];
                }
            }
        }

        // ---------- norm clip per tile ----------
#pragma unroll
        for (int bt = 0; bt < 2; ++bt) {
            float ss = 0.0f;
#pragma unroll
            for (int s = 0; s < 64; ++s) ss += hr[bt][s] * hr[bt][s];
            ss += __shfl_xor(ss, 16);
            ss += __shfl_xor(ss, 32);
            const float n = sqrtf(ss);
            const float sc = (n > 10.0f) ? (10.0f / (n + 1e-8f)) : 1.0f;
#pragma unroll
            for (int s = 0; s < 64; ++s) hr[bt][s] *= sc;
        }
    }

    // ---------- store h_final ----------
#pragma unroll
    for (int bt = 0; bt < 2; ++bt) {
#pragma unroll
        for (int mt = 0; mt < 16; ++mt) {
            float4 v;
            v.x = hr[bt][mt*4+0]; v.y = hr[bt][mt*4+1];
            v.z = hr[bt][mt*4+2]; v.w = hr[bt][mt*4+3];
            *(float4*)&out_h[(size_t)(bg + bt*16) * DIMX + 16 * mt + 4 * G] = v;
        }
    }
}

extern "C" void kernel_launch(void* const* d_in, const int* in_sizes, int n_in,
                              void* d_out, int out_size, void* d_ws, size_t ws_size,
                              hipStream_t stream) {
    const float* h0      = (const float*)d_in[0];
    const float* W1      = (const float*)d_in[1];
    const float* b1      = (const float*)d_in[2];
    const float* W2      = (const float*)d_in[3];
    const float* b2      = (const float*)d_in[4];
    const float* anchors = (const float*)d_in[5];
    const int B = in_sizes[0] / DIMX;

    float* out_h     = (float*)d_out;
    float* out_align = out_h + (long long)B * DIMX;
    float* out_div   = out_align + (long long)NL * B * 3;
    float* out_tens  = out_div   + (long long)NL * B * 3;

    u32x4* ws = (u32x4*)d_ws;   // 280 KiB

    hipLaunchKernelGGL(wsplit, dim3(70), dim3(256), 0, stream, W1, W2, anchors, b2, ws);
    hipLaunchKernelGGL(collapse_mfma16, dim3(B / 256), dim3(512), 0, stream,
                       h0, b1, ws,
                       out_h, out_align, out_div, out_tens, B);
}

// Round 21
// 327.797 us; speedup vs baseline: 1.7046x; 1.7046x over previous
//
#include <hip/hip_runtime.h>
#include <math.h>

// CollapseEngine R21: W-resident with CORRECT LDS arithmetic.
// R19/R20 bug (identical deterministic absmax 3.89): "12 resident chunks in
// 96KB" -- 12 chunks are 192KB; wfr[6144] holds 6. Writes overflowed into
// wfs/wext/wstat. Fixed: chunks 0-5 resident (96KB, barrier-free reads),
// chunks 6-15 streamed through a 32KB 2-slot dbuf, R5-proven window order
// (vmcnt(0) on loads issued one window earlier -> s_barrier -> stage next).
// 10 barriers/layer (vs R15's 16). Math bit-identical to R15 (333us champion).
// phi(ks,G,i) = 32*ks + 16*(i>>2) + 4*G + (i&3),  G = lane>>4.

#define DIMX 256
#define NL 6
#define CPAD 68

typedef float f32x4 __attribute__((ext_vector_type(4)));
typedef short short8 __attribute__((ext_vector_type(8)));
typedef unsigned int u32x4 __attribute__((ext_vector_type(4)));

#define CHB(c) ((c) * 1024)
#define EXTB 16384      // ext A-frags (G2 force fold): 1024 granules
#define STATB 17408     // stats A-frags: 512 granules

// RNE-pack f32 pair -> u32 of 2 bf16 (lo = X0, hi = X1)
#define PACKB(X0, X1, DST)                                                       \
    asm("v_cvt_pk_bf16_f32 %0, %1, %2" : "=v"(DST) : "v"(X0), "v"(X1));

// ---------------- W frag + ext/stat frag precompute (= R15, verbatim) ----------
__global__ void wsplit(const float* __restrict__ W1, const float* __restrict__ W2,
                       const float* __restrict__ anchors, const float* __restrict__ b2f,
                       u32x4* __restrict__ ws) {
    int gi = blockIdx.x * 256 + threadIdx.x;        // 0..17919
    if (gi < 16384) {
        int ln   = gi & 63;
        int t8   = (gi >> 6) & 7;
        int ks2  = (gi >> 9) & 1;
        int kk   = (gi >> 10) & 3;
        int pass = (gi >> 12) & 1;
        int g    = (gi >> 13) & 1;
        int ks   = kk * 2 + ks2;
        int m    = (pass * 8 + t8) * 16 + (ln & 15);
        int G    = ln >> 4;
        const float* Wg = g ? W2 : W1;
        unsigned o[4];
#pragma unroll
        for (int p = 0; p < 4; ++p) {
            int f = 32 * ks + ((p >> 1) << 4) + 4 * G + ((p & 1) << 1);
            float x0 = Wg[m * DIMX + f];
            float x1 = Wg[m * DIMX + f + 1];
            unsigned hp;
            PACKB(x0, x1, hp);
            o[p] = hp;
        }
        u32x4 out = {o[0], o[1], o[2], o[3]};
        ws[gi] = out;
    } else if (gi < STATB) {
        int r    = gi - EXTB;
        int pass = r >> 9;
        int t8   = (r >> 6) & 7;
        int ln   = r & 63;
        int m    = ln & 15;
        int G    = ln >> 4;
        int fout = (pass * 8 + t8) * 16 + m;
        float inv[3];
#pragma unroll
        for (int k = 0; k < 3; ++k) {
            float ss = 0.0f;
            for (int f = 0; f < DIMX; ++f) { float a = anchors[k*DIMX+f]; ss += a*a; }
            inv[k] = 1.0f / fmaxf(sqrtf(ss), 1e-12f);
        }
        float v[8];
#pragma unroll
        for (int i = 0; i < 8; ++i) {
            int k = G * 8 + i;
            v[i] = (k == 0) ? -anchors[fout] * inv[0]
                 : (k == 1) ? -anchors[DIMX + fout] * inv[1]
                 : (k == 2) ? -anchors[2 * DIMX + fout] * inv[2]
                 : (k == 3) ? b2f[fout] : 0.0f;
        }
        unsigned o[4];
#pragma unroll
        for (int p = 0; p < 4; ++p) { unsigned hp; PACKB(v[2*p], v[2*p+1], hp); o[p] = hp; }
        u32x4 out = {o[0], o[1], o[2], o[3]};
        ws[gi] = out;
    } else if (gi < STATB + 512) {
        int r  = gi - STATB;
        int ks = r >> 6;
        int ln = r & 63;
        int m  = ln & 15;
        int G  = ln >> 4;
        float inv = 0.0f;
        if (m < 3) {
            float ss = 0.0f;
            for (int f = 0; f < DIMX; ++f) { float a = anchors[m*DIMX+f]; ss += a*a; }
            inv = 1.0f / fmaxf(sqrtf(ss), 1e-12f);
        }
        float v[8];
#pragma unroll
        for (int i = 0; i < 8; ++i) {
            int f = 32 * ks + 16 * (i >> 2) + 4 * G + (i & 3);
            v[i] = (m < 3) ? anchors[m * DIMX + f] * inv : 0.0f;
        }
        unsigned o[4];
#pragma unroll
        for (int p = 0; p < 4; ++p) { unsigned hp; PACKB(v[2*p], v[2*p+1], hp); o[p] = hp; }
        u32x4 out = {o[0], o[1], o[2], o[3]};
        ws[gi] = out;
    }
}

// ---------------- main fused kernel ----------------

#define STAGE_TO(gIdxBase, ARR, ldsSlotBase)                                     \
    {                                                                            \
        _Pragma("unroll")                                                        \
        for (int i_ = 0; i_ < 2; ++i_) {                                         \
            const int off_ = ((w * 2 + i_) << 6);                                \
            __builtin_amdgcn_global_load_lds(                                    \
                (const __attribute__((address_space(1))) void*)(ws + (gIdxBase) + off_ + lane), \
                (__attribute__((address_space(3))) void*)(&ARR[(ldsSlotBase) + off_]),          \
                16, 0, 0);                                                       \
        }                                                                        \
    }

// Streamed window, pos = compile-time position 0..9 (chunk 6+pos):
// drain own loads of chunk 6+pos (issued one window earlier), barrier
// (=> all waves' loads complete, all readers of the refill slot are past),
// then issue chunk 6+((pos+1)%10) into the other slot.
#define WINDOW(pos)                                                              \
    {                                                                            \
        asm volatile("s_waitcnt vmcnt(0)" ::: "memory");                         \
        __builtin_amdgcn_sched_barrier(0);                                       \
        __builtin_amdgcn_s_barrier();                                            \
        __builtin_amdgcn_sched_barrier(0);                                       \
        STAGE_TO(CHB(6 + (((pos) + 1) % 10)), wfs, ((((pos) + 1) & 1)) * 1024);  \
    }

__global__ __launch_bounds__(512, 2)
void collapse_mfma16(const float* __restrict__ h0,
                     const float* __restrict__ b1f,
                     const u32x4* __restrict__ ws,
                     float* __restrict__ out_h,
                     float* __restrict__ out_align,
                     float* __restrict__ out_div,
                     float* __restrict__ out_tens,
                     int B)
{
    __shared__ __align__(16) u32x4 wfr[6144];        // 96KB: resident chunks 0-5
    __shared__ __align__(16) u32x4 wfs[2048];        // 32KB: 2-slot stream dbuf
    __shared__ __align__(16) u32x4 wext[1024];       // 16KB ext A-frags
    __shared__ __align__(16) u32x4 wstat[512];       // 8KB stats A-frags
    __shared__ __align__(16) float b1_reg[272];      // ~1KB. Total ~153KB <= 160KB

    const int tid  = threadIdx.x;
    const int w    = tid >> 6;
    const int lane = tid & 63;
    const int G    = lane >> 4;
    const int c    = lane & 15;
    const int bglob = blockIdx.x * 128 + w * 16 + c;

    // statics + resident chunks 0..5 + stream chunk 6 (drained by init sync)
    {
#pragma unroll
        for (int i_ = 0; i_ < 2; ++i_) {
            const int off_ = ((w * 2 + i_) << 6);
            __builtin_amdgcn_global_load_lds(
                (const __attribute__((address_space(1))) void*)(ws + EXTB + off_ + lane),
                (__attribute__((address_space(3))) void*)(&wext[off_]),
                16, 0, 0);
        }
        __builtin_amdgcn_global_load_lds(
            (const __attribute__((address_space(1))) void*)(ws + STATB + w*64 + lane),
            (__attribute__((address_space(3))) void*)(&wstat[w*64]),
            16, 0, 0);
#pragma unroll
        for (int cch = 0; cch < 6; ++cch) STAGE_TO(CHB(cch), wfr, cch * 1024);
        STAGE_TO(CHB(6), wfs, 0);
    }

    // b1 in phi-layout, padded
    {
        int idx = tid & 255;
        int Gc = idx >> 6, s = idx & 63;
        int f = 16 * (s >> 2) + 4 * Gc + (s & 3);
        if (tid < 256) b1_reg[Gc * CPAD + s] = b1f[f];
    }
    __syncthreads();

    // load h0 into phi-layout regs
    float hr[64];
#pragma unroll
    for (int mt = 0; mt < 16; ++mt) {
        const float4 v = *(const float4*)&h0[(size_t)bglob * DIMX + 16 * mt + 4 * G];
        hr[mt * 4 + 0] = v.x; hr[mt * 4 + 1] = v.y;
        hr[mt * 4 + 2] = v.z; hr[mt * 4 + 3] = v.w;
    }

#pragma unroll 1
    for (int layer = 0; layer < NL; ++layer) {
        // ---------- p0 = |h|^2 ----------
        float p0 = 0;
#pragma unroll
        for (int s = 0; s < 64; ++s) p0 += hr[s] * hr[s];
        p0 += __shfl_xor(p0, 16);
        p0 += __shfl_xor(p0, 32);

        // ---------- G1 (+ stats tile in pass 0) ----------
        // pass0: chunks 0-3 resident (barrier-free). pass1: kk 0,1 resident
        // (chunks 4,5); kk 2,3 streamed (pos 0,1 = chunks 6,7).
        unsigned tph[32];
        f32x4 acs = (f32x4)(0.0f);
#pragma unroll
        for (int pass = 0; pass < 2; ++pass) {
            f32x4 ac[8];
#pragma unroll
            for (int j = 0; j < 8; ++j) ac[j] = (f32x4)(0.0f);
#pragma unroll
            for (int kk = 0; kk < 4; ++kk) {
                const int s = pass * 4 + kk;
                const bool streamed = (s >= 6);
                if (pass == 1 && kk == 2) WINDOW(0);
                if (pass == 1 && kk == 3) WINDOW(1);
                const int cb = streamed ? ((s - 6) & 1) * 1024 : s * 1024;
#pragma unroll
                for (int ks2 = 0; ks2 < 2; ++ks2) {
                    const int ks = kk * 2 + ks2;
                    unsigned bh[4];
#pragma unroll
                    for (int p = 0; p < 4; ++p)
                        PACKB(hr[8*ks + 2*p], hr[8*ks + 2*p + 1], bh[p]);
                    u32x4 thi = {bh[0], bh[1], bh[2], bh[3]};
                    const short8 Bh = __builtin_bit_cast(short8, thi);
#pragma unroll
                    for (int j = 0; j < 8; ++j) {
                        const short8 Ah = streamed
                            ? __builtin_bit_cast(short8, wfs[cb + ks2*512 + j*64 + lane])
                            : __builtin_bit_cast(short8, wfr[cb + ks2*512 + j*64 + lane]);
                        ac[j] = __builtin_amdgcn_mfma_f32_16x16x32_bf16(Ah, Bh, ac[j], 0, 0, 0);
                    }
                    if (pass == 0) {
                        const short8 As = __builtin_bit_cast(short8, wstat[ks*64 + lane]);
                        acs = __builtin_amdgcn_mfma_f32_16x16x32_bf16(As, Bh, acs, 0, 0, 0);
                    }
                }
            }
            // tanh + b1, pack into t
#pragma unroll
            for (int j = 0; j < 8; ++j) {
                const int mt = pass * 8 + j;
                const float4 bq = *(const float4*)&b1_reg[G * CPAD + mt * 4];
                float tv[4];
#pragma unroll
                for (int r = 0; r < 4; ++r) {
                    float x = ac[j][r] + ((r==0)?bq.x:(r==1)?bq.y:(r==2)?bq.z:bq.w);
                    float e = __expf(2.0f * x);
                    tv[r] = 1.0f - 2.0f * __builtin_amdgcn_rcpf(e + 1.0f);
                }
                const int ti = 4 * (mt >> 1) + 2 * (mt & 1);
                PACKB(tv[0], tv[1], tph[ti]);
                PACKB(tv[2], tv[3], tph[ti + 1]);
            }
        }

        // ---------- stats finish ----------
        const float d0 = acs[0], d1 = acs[1], d2 = acs[2];
        const float inv_rn = 1.0f / fmaxf(sqrtf(p0), 1e-12f);
        const float al0 = d0 * inv_rn, al1 = d1 * inv_rn, al2 = d2 * inv_rn;
        const float dv0 = 1.0f - al0, dv1 = 1.0f - al1, dv2 = 1.0f - al2;
        const float c0 = -0.10f * dv0 / fmaxf(sqrtf(fmaxf(p0 - 2.0f*d0 + 1.0f, 0.0f)), 1e-12f);
        const float c1 = -0.10f * dv1 / fmaxf(sqrtf(fmaxf(p0 - 2.0f*d1 + 1.0f, 0.0f)), 1e-12f);
        const float c2 = -0.05f * dv2 / fmaxf(sqrtf(fmaxf(p0 - 2.0f*d2 + 1.0f, 0.0f)), 1e-12f);
        if (G == 0) {
            const long long tb = ((long long)layer * B + bglob) * 3;
            out_align[tb+0] = al0; out_align[tb+1] = al1; out_align[tb+2] = al2;
            out_div[tb+0] = dv0;   out_div[tb+1] = dv1;   out_div[tb+2] = dv2;
            out_tens[tb+0] = dv0*dv0; out_tens[tb+1] = dv1*dv1; out_tens[tb+2] = dv2*dv2;
        }
        unsigned be0 = 0, be1 = 0;
        if (G == 0) { PACKB(c0, c1, be0); PACKB(c2, 1.0f, be1); }
        u32x4 bev = {be0, be1, 0u, 0u};
        const short8 Bext = __builtin_bit_cast(short8, bev);
        float csum = 1.0f + c0 + c1 + c2;
        csum = __shfl(csum, c);

        // ---------- G2: pass0 = stream pos 2-5 (chunks 8-11),
        //            pass1 = stream pos 6-9 (chunks 12-15) ----------
#pragma unroll
        for (int pass = 0; pass < 2; ++pass) {
            f32x4 ac[8];
#pragma unroll
            for (int j = 0; j < 8; ++j) {
                const int mt = pass * 8 + j;
                ac[j][0] = hr[mt*4+0]*csum;
                ac[j][1] = hr[mt*4+1]*csum;
                ac[j][2] = hr[mt*4+2]*csum;
                ac[j][3] = hr[mt*4+3]*csum;
            }
#pragma unroll
            for (int j = 0; j < 8; ++j) {
                const short8 Ax = __builtin_bit_cast(short8, wext[pass*512 + j*64 + lane]);
                ac[j] = __builtin_amdgcn_mfma_f32_16x16x32_bf16(Ax, Bext, ac[j], 0, 0, 0);
            }
#pragma unroll
            for (int kk = 0; kk < 4; ++kk) {
                const int pos = 2 + pass * 4 + kk;   // 2..9
                if (pos == 2) WINDOW(2); if (pos == 3) WINDOW(3);
                if (pos == 4) WINDOW(4); if (pos == 5) WINDOW(5);
                if (pos == 6) WINDOW(6); if (pos == 7) WINDOW(7);
                if (pos == 8) WINDOW(8); if (pos == 9) WINDOW(9);
                const int cb = (pos & 1) * 1024;
#pragma unroll
                for (int ks2 = 0; ks2 < 2; ++ks2) {
                    const int ks = kk * 2 + ks2;
                    u32x4 thi = {tph[4*ks+0], tph[4*ks+1], tph[4*ks+2], tph[4*ks+3]};
                    const short8 Bh = __builtin_bit_cast(short8, thi);
#pragma unroll
                    for (int j = 0; j < 8; ++j) {
                        const short8 Ah = __builtin_bit_cast(short8,
                            wfs[cb + ks2*512 + j*64 + lane]);
                        ac[j] = __builtin_amdgcn_mfma_f32_16x16x32_bf16(Ah, Bh, ac[j], 0, 0, 0);
                    }
                }
            }
#pragma unroll
            for (int j = 0; j < 8; ++j) {
                const int mt = pass * 8 + j;
                hr[mt*4+0] = ac[j][0]; hr[mt*4+1] = ac[j][1];
                hr[mt*4+2] = ac[j][2]; hr[mt*4+3] = ac[j][3];
            }
        }

        // ---------- norm clip ----------
        {
            float ss = 0.0f;
#pragma unroll
            for (int s = 0; s < 64; ++s) ss += hr[s] * hr[s];
            ss += __shfl_xor(ss, 16);
            ss += __shfl_xor(ss, 32);
            const float n = sqrtf(ss);
            const float sc = (n > 10.0f) ? (10.0f / (n + 1e-8f)) : 1.0f;
#pragma unroll
            for (int s = 0; s < 64; ++s) hr[s] *= sc;
        }
    }

    // ---------- store h_final ----------
#pragma unroll
    for (int mt = 0; mt < 16; ++mt) {
        float4 v;
        v.x = hr[mt*4+0]; v.y = hr[mt*4+1]; v.z = hr[mt*4+2]; v.w = hr[mt*4+3];
        *(float4*)&out_h[(size_t)bglob * DIMX + 16 * mt + 4 * G] = v;
    }
}

extern "C" void kernel_launch(void* const* d_in, const int* in_sizes, int n_in,
                              void* d_out, int out_size, void* d_ws, size_t ws_size,
                              hipStream_t stream) {
    const float* h0      = (const float*)d_in[0];
    const float* W1      = (const float*)d_in[1];
    const float* b1      = (const float*)d_in[2];
    const float* W2      = (const float*)d_in[3];
    const float* b2      = (const float*)d_in[4];
    const float* anchors = (const float*)d_in[5];
    const int B = in_sizes[0] / DIMX;

    float* out_h     = (float*)d_out;
    float* out_align = out_h + (long long)B * DIMX;
    float* out_div   = out_align + (long long)NL * B * 3;
    float* out_tens  = out_div   + (long long)NL * B * 3;

    u32x4* ws = (u32x4*)d_ws;   // 280 KiB (16384 W + 1024 ext + 512 stat)

    hipLaunchKernelGGL(wsplit, dim3(70), dim3(256), 0, stream, W1, W2, anchors, b2, ws);
    hipLaunchKernelGGL(collapse_mfma16, dim3(B / 128), dim3(512), 0, stream,
                       h0, b1, ws,
                       out_h, out_align, out_div, out_tens, B);
}